// Round 8
// baseline (60.565 us; speedup 1.0000x reference)
//
#include <hip/hip_runtime.h>
#include <stdint.h>

// DCN forward: B=4, H=128, W=128, G=8, C=32, K=8
// inputs      [B,H,W,G,C]   fp32
// deformables [B,H,W,G,K,2] fp32
// weights     [B,H,W,G,K]   fp32
// out         [B,H,W,G,C]   fp32
//
// R8 = R7 with the corner-clamp bug fixed.
//  - 8 lanes/pixel: each ds_read_b128 8-lane phase = ONE pixel reading slots
//    0..7 of one cell -> with odd slot-plane pitch (257), bank groups
//    (c4 + cell) mod 8 are all distinct: zero LDS conflicts by construction.
//  - LDS layout [slot 8][pitch 257] float4: gather idx = ibase + (yf<<4) + xf
//  - RH=4 halo (16x16 cells, 32.9 KB) -> 4 blocks/CU
//  - branch BEFORE reads on inh = |dx|<4 & |dy|<4 (conservative, proven incl.
//    edge clamps); rare fallback does the identical-semantics global gather.
//  - CORRECT corner clamps: xc = clip(fx+1, 0, 127) (NOT min(xf+1,127) --
//    for x in (-2,-1], fx=-1, reference reads column 0 with nonzero weight).

#define Bc 4
#define Hc 128
#define Wc 128
#define Gc 8
#define Cc 32
#define Kc 8
#define TH 8
#define TW 8
#define RH 4
#define PITCH 257      // odd -> conflict-free slot planes; >= 256 cells
#define NF4S (8*PITCH) // 2056 float4 = 32896 B

typedef float float4v __attribute__((ext_vector_type(4)));

__global__ __launch_bounds__(512, 8) void dcn_fwd(
    const float* __restrict__ inp,
    const float* __restrict__ def,
    const float* __restrict__ wts,
    float* __restrict__ out)
{
    const int tid = threadIdx.x;
    const int c4  = tid & 7;      // slot: 4 channels
    const int px  = tid >> 3;     // 0..63 pixel in tile
    const int pw  = px & 7;
    const int ph  = px >> 3;

    // grid: wt(16), ht(16), g(8), b(4)
    const int blk = blockIdx.x;
    const int wt = blk & 15;
    const int ht = (blk >> 4) & 15;
    const int g  = (blk >> 8) & 7;
    const int b  = blk >> 11;

    const int h0 = ht * TH, w0 = wt * TW;
    const int row0 = h0 - RH, col0 = w0 - RH;   // window origin (may be <0)

    // global plane as float4 units: index = y*8192 + x*64 + u
    const float4v* gp4 = (const float4v*)((const char*)inp
        + ((size_t)b << 24) + ((size_t)g << 7));

    __shared__ float4v tile[NF4S];

    // ---- stage 16x16 cell window into [slot][pitch] layout ----
#pragma unroll
    for (int r = 0; r < 4; ++r) {
        const int idx  = r * 512 + tid;          // 2048 float4 total
        const int cell = idx >> 3;
        const int u    = idx & 7;
        const int rr   = cell >> 4;
        const int cc   = cell & 15;
        const int gr   = min(max(row0 + rr, 0), Hc - 1);
        const int gc   = min(max(col0 + cc, 0), Wc - 1);
        tile[u * PITCH + cell] = gp4[gr * 8192 + gc * 64 + u];
    }
    __syncthreads();

    const int h = h0 + ph;
    const int w = w0 + pw;
    const int pg = ((b * Hc + h) * Wc + w) * Gc + g;

    // vectorized def/wts loads
    const float4v d0 = *(const float4v*)(def + (size_t)pg * 16 + 0);
    const float4v d1 = *(const float4v*)(def + (size_t)pg * 16 + 4);
    const float4v d2 = *(const float4v*)(def + (size_t)pg * 16 + 8);
    const float4v d3 = *(const float4v*)(def + (size_t)pg * 16 + 12);
    const float4v q0 = *(const float4v*)(wts + (size_t)pg * 8 + 0);
    const float4v q1 = *(const float4v*)(wts + (size_t)pg * 8 + 4);

    const float dxs[8] = {d0.x, d0.z, d1.x, d1.z, d2.x, d2.z, d3.x, d3.z};
    const float dys[8] = {d0.y, d0.w, d1.y, d1.w, d2.y, d2.w, d3.y, d3.w};
    const float wks[8] = {q0.x, q0.y, q0.z, q0.w, q1.x, q1.y, q1.z, q1.w};

    const float wf = (float)w;
    const float hf = (float)h;

    // tile index = c4*PITCH + (yf-row0)*16 + (xf-col0) = ibase + (yf<<4) + xf
    const int ibase = c4 * PITCH - (row0 << 4) - col0;

    float4v acc0 = {0.f, 0.f, 0.f, 0.f};
    float4v acc1 = {0.f, 0.f, 0.f, 0.f};

#pragma unroll
    for (int k = 0; k < Kc; ++k) {
        const float dx = dxs[k];
        const float dy = dys[k];

        const float x = dx + wf;
        const float y = dy + hf;

        // truncation toward zero, matching .astype(int32)
        const int fx = (int)x;
        const int fy = (int)y;

        const float wx1 = x - (float)fx;       // exact
        const float wy1 = y - (float)fy;
        const float wx0 = 1.0f - wx1;          // bit-equal to cxf - x
        const float wy0 = 1.0f - wy1;

        // image-bounds mask via unsigned compare (cx=fx+1, cy=fy+1)
        const float ax0 = ((uint32_t)fx       < (uint32_t)Wc) ? wx0 : 0.f;
        const float ax1 = ((uint32_t)(fx + 1) < (uint32_t)Wc) ? wx1 : 0.f;
        const float ay0 = ((uint32_t)fy       < (uint32_t)Hc) ? wy0 : 0.f;
        const float ay1 = ((uint32_t)(fy + 1) < (uint32_t)Hc) ? wy1 : 0.f;

        // TRUE reference clamps for all four corners
        const int xf = min(max(fx,     0), Wc - 1);
        const int xc = min(max(fx + 1, 0), Wc - 1);
        const int yf = min(max(fy,     0), Hc - 1);
        const int yc = min(max(fy + 1, 0), Hc - 1);

        const float wk = wks[k];
        const float ay0k = wk * ay0;
        const float ay1k = wk * ay1;
        const float c00 = ay0k * ax0;
        const float c01 = ay0k * ax1;
        const float c10 = ay1k * ax0;
        const float c11 = ay1k * ax1;

        // conservative containment: |dx|<4 & |dy|<4 => all 4 corners staged
        const bool inh = (fabsf(dx) < 4.0f) & (fabsf(dy) < 4.0f);
        if (__builtin_expect(inh, 1)) {
            const int yA = yf << 4;
            const int yB = yc << 4;
            acc0 += c00 * tile[ibase + yA + xf];
            acc1 += c01 * tile[ibase + yA + xc];
            acc0 += c10 * tile[ibase + yB + xf];
            acc1 += c11 * tile[ibase + yB + xc];
        } else {
            acc0 += c00 * gp4[yf * 8192 + xf * 64 + c4];
            acc1 += c01 * gp4[yf * 8192 + xc * 64 + c4];
            acc0 += c10 * gp4[yc * 8192 + xf * 64 + c4];
            acc1 += c11 * gp4[yc * 8192 + xc * 64 + c4];
        }
    }

    const float4v acc = acc0 + acc1;
    ((float4v*)((char*)out + (size_t)pg * 128))[c4] = acc;
}

extern "C" void kernel_launch(void* const* d_in, const int* in_sizes, int n_in,
                              void* d_out, int out_size, void* d_ws, size_t ws_size,
                              hipStream_t stream) {
    const float* inp = (const float*)d_in[0];
    const float* def = (const float*)d_in[1];
    const float* wts = (const float*)d_in[2];
    float* out = (float*)d_out;

    const int nblocks = Bc * Gc * (Hc / TH) * (Wc / TW);  // 8192
    dcn_fwd<<<nblocks, 512, 0, stream>>>(inp, def, wts, out);
}